// Round 10
// baseline (458.591 us; speedup 1.0000x reference)
//
#include <hip/hip_runtime.h>
#include <math.h>

// LotkaVolterra neural-SDE rollout. P=4096, H=256, 100 sequential steps.
// R10: LDS A-read redundancy is the binding constraint (8KB x #MFMA-waves).
// Go to 4 waves x 4 col-groups (NT=256, 1 wave/SIMD): at 1 wave/SIMD the
// 512-reg file fits wf1+wf2 = 256 weight VGPRs without spill. A-reads drop
// 256 -> 64 b128/step. Epilogue packed b32 writes (shfl_xor parity trick).
// Layer3+sampling redundant in all 4 waves (st in regs, 3 barriers/step).
// FETCH_SIZE ~4MB is the spill tripwire (R6: GB-scale = weights spilled).

#define PP 4096
#define HH 256
#define LT 100
#define PB 16
#define SH 264          // bf16 LDS row stride: 528 B
#define NT 256

typedef __attribute__((ext_vector_type(8))) short short8;
typedef __attribute__((ext_vector_type(4))) short short4v;
typedef __attribute__((ext_vector_type(4))) float float4v;

__device__ __forceinline__ float softplus_fast(float x) {
    const float e = __expf(-fabsf(x));
    return fmaxf(x, 0.0f) + __logf(1.0f + e);
}
__device__ __forceinline__ unsigned short f2bf(float f) {   // RNE fp32->bf16
    unsigned int u = __float_as_uint(f);
    u += 0x7fffu + ((u >> 16) & 1u);
    return (unsigned short)(u >> 16);
}
__device__ __forceinline__ float4 ldg4(const float* p) { return *(const float4*)p; }

// ---- prologue: weight fragments (blocks 0..527) + cfeat table (block 528) ----
__global__ void prep_weights(const float* __restrict__ W0, const float* __restrict__ b0,
                             const float* __restrict__ W1, const float* __restrict__ W2,
                             const float* __restrict__ W3,
                             const float* __restrict__ feature_init,
                             const float* __restrict__ tn_store,
                             const float* __restrict__ x1_store,
                             const float* __restrict__ x2_store,
                             unsigned short* __restrict__ wt,
                             float* __restrict__ cfeat) {
    const int b = blockIdx.x;
    if (b < 528) {
        const int i = b * 256 + threadIdx.x;
        if (i < 131072) {
            const int m = i >> 16;            // 0 = W1, 1 = W2
            const int ii = i & 65535;
            const int k = ii >> 8, n = ii & 255;
            const float* W = m ? W2 : W1;
            const float val = W[ii];
            const int ks = k >> 5, quad = (k >> 3) & 3, j = k & 7;
            const int cg = n >> 4, c = n & 15;
            const int lane = quad * 16 + c;
            wt[m * 65536 + ((cg * 8 + ks) * 64 + lane) * 8 + j] = f2bf(val);
        } else if (i < 135168) {
            const int ii = i - 131072;
            const int j = ii & 7, lane = (ii >> 3) & 63, ks = ii >> 9;
            const int k = ks * 32 + (lane >> 4) * 8 + j;
            const int n = lane & 15;
            wt[i] = (n < 5) ? f2bf(W3[k * 5 + n]) : (unsigned short)0;
        }
    } else {
        const int col = threadIdx.x;          // 256 threads
        float tval = feature_init[0];         // t0; fp32 chain matches ref
        const float w2c = W0[2 * 256 + col], w3c = W0[3 * 256 + col];
        const float w46 = W0[4 * 256 + col] + W0[6 * 256 + col];
        const float w57 = W0[5 * 256 + col] + W0[7 * 256 + col];
        const float bc = b0[col];
        for (int t = 1; t < LT; ++t) {
            tval += 0.1f;
            const float tn = tn_store[t - 1], x1 = x1_store[t - 1], x2 = x2_store[t - 1];
            cfeat[t * 256 + col] = bc + tval * w2c + tn * w3c + x1 * w46 + x2 * w57;
        }
    }
}

// 256->256 bf16 MFMA layer: 4 col-groups per wave, B from registers.
// A-frags read once, reused by all 4 cg (the redundancy fix).
__device__ __forceinline__ void layer4cg(const short8* __restrict__ wf,   // 32 frags
                                         const float* __restrict__ bv,    // 4 biases
                                         const unsigned short* __restrict__ hin,
                                         unsigned short* __restrict__ hout,
                                         int wv, int lane) {
    const int quad = lane >> 4, col = lane & 15;
    const unsigned short* arow = hin + col * SH + quad * 8;
    short8 a[8];
#pragma unroll
    for (int ks = 0; ks < 8; ++ks) a[ks] = *(const short8*)(arow + ks * 32);
    float4v acc[4];
#pragma unroll
    for (int i = 0; i < 4; ++i) acc[i] = (float4v){bv[i], bv[i], bv[i], bv[i]};
#pragma unroll
    for (int ks = 0; ks < 8; ++ks)
#pragma unroll
        for (int i = 0; i < 4; ++i)
            acc[i] = __builtin_amdgcn_mfma_f32_16x16x32_bf16(a[ks], wf[i * 8 + ks], acc[i], 0, 0, 0);
    // packed epilogue: 2 cols per b32 write; even lanes rows q4+{0,1}, odd q4+{2,3}
    const int odd = lane & 1;
#pragma unroll
    for (int i = 0; i < 4; ++i) {
        const unsigned int u0 = f2bf(fmaxf(acc[i][0], 0.0f));
        const unsigned int u1 = f2bf(fmaxf(acc[i][1], 0.0f));
        const unsigned int u2 = f2bf(fmaxf(acc[i][2], 0.0f));
        const unsigned int u3 = f2bf(fmaxf(acc[i][3], 0.0f));
        const unsigned int n0 = (unsigned int)__shfl_xor((int)u0, 1);
        const unsigned int n1 = (unsigned int)__shfl_xor((int)u1, 1);
        const unsigned int n2 = (unsigned int)__shfl_xor((int)u2, 1);
        const unsigned int n3 = (unsigned int)__shfl_xor((int)u3, 1);
        const unsigned int dA = odd ? (n2 | (u2 << 16)) : (u0 | (n0 << 16));
        const unsigned int dB = odd ? (n3 | (u3 << 16)) : (u1 | (n1 << 16));
        const int row0 = quad * 4 + (odd ? 2 : 0);
        const int cb = (wv * 4 + i) * 16 + (col & ~1);
        *(unsigned int*)&hout[row0 * SH + cb] = dA;
        *(unsigned int*)&hout[(row0 + 1) * SH + cb] = dB;
    }
}

__global__ __launch_bounds__(NT, 1)
void lv_kernel(const float* __restrict__ W0, const float* __restrict__ b0,
               const float* __restrict__ b1, const float* __restrict__ b2,
               const float* __restrict__ b3,
               const float* __restrict__ obs_init, const float* __restrict__ feature_init,
               const float* __restrict__ path_seed,
               const unsigned short* __restrict__ wt,
               const float* __restrict__ cfeat,
               float* __restrict__ out) {
    __shared__ unsigned short hA[PB * SH];
    __shared__ unsigned short hB[PB * SH];
    __shared__ unsigned short hC[PB * SH];
    __shared__ __align__(16) unsigned short w3l[4096];   // W3 fragments
    __shared__ float sc[4][16][5];                       // per-wave o3 scratch
    __shared__ __align__(16) float pbuf[PB * 202];
    __shared__ __align__(16) float mbuf[PB * 200];
    __shared__ __align__(16) float sbuf[PB * 400];

    const int tid = threadIdx.x;
    const int lane = tid & 63;
    const int wv = tid >> 6;            // wave 0..3; owns col-groups 4wv..4wv+3
    const int quad = lane >> 4;
    const int col = lane & 15;
    const int pbase = blockIdx.x * PB;

    const float DTf = 0.1f;
    const float SQ = 0.31622776601683794f;  // sqrt(0.1)

    const unsigned short* Wt1 = wt;
    const unsigned short* Wt2 = wt + 65536;
    const unsigned short* Wt3 = wt + 131072;

    // ---- stage w3l (8 KB) ----
    ((float4*)w3l)[tid] = ((const float4*)Wt3)[tid];
    ((float4*)w3l)[tid + 256] = ((const float4*)Wt3)[tid + 256];

    // ---- per-wave weight fragments: 256 VGPRs (fits at 1 wave/SIMD) ----
    short8 wf1[32], wf2[32];
#pragma unroll
    for (int i = 0; i < 4; ++i)
#pragma unroll
        for (int ks = 0; ks < 8; ++ks) {
            const int idx = (((wv * 4 + i) * 8 + ks) * 64 + lane) * 8;
            wf1[i * 8 + ks] = *(const short8*)(Wt1 + idx);
            wf2[i * 8 + ks] = *(const short8*)(Wt2 + idx);
        }

    // step-invariant hoists
    float bv1[4], bv2[4];
#pragma unroll
    for (int i = 0; i < 4; ++i) {
        bv1[i] = b1[(wv * 4 + i) * 16 + col];
        bv2[i] = b2[(wv * 4 + i) * 16 + col];
    }
    const float b3c = (col < 5) ? b3[col] : 0.0f;

    // layer-0 constants: W0 rows 0,1 for this lane's 4 cols (register-resident)
    const int c0 = lane * 4;
    const float4 wa = ldg4(W0 + c0);
    const float4 wb = ldg4(W0 + HH + c0);

    // per-path state in registers, lanes<16 of EVERY wave (redundant sampling)
    float st0 = 0.0f, st1 = 0.0f;
    float ft0 = 0, ft1 = 0, ft2 = 0, ft3 = 0, ft4 = 0, ft5 = 0;
    if (lane < 16) {
        const int gp = pbase + lane;
        st0 = obs_init[gp * 2 + 0];
        st1 = obs_init[gp * 2 + 1];
        ft0 = feature_init[gp * 6 + 0]; ft1 = feature_init[gp * 6 + 1];
        ft2 = feature_init[gp * 6 + 2]; ft3 = feature_init[gp * 6 + 3];
        ft4 = feature_init[gp * 6 + 4]; ft5 = feature_init[gp * 6 + 5];
    }
    if (wv == 0 && lane < PB) {
        const int p = lane;
        pbuf[p * 202 + 0] = st0;
        pbuf[p * 202 + 101] = st1;
    }

    // ---- t=0 layer 0: per-path features (one-time); wave wv -> paths 4wv..4wv+3 ----
    {
        const float4 bc = ldg4(b0 + c0);
        const float4 w2 = ldg4(W0 + 2 * HH + c0);
        const float4 w3_ = ldg4(W0 + 3 * HH + c0);
        const float4 w4 = ldg4(W0 + 4 * HH + c0);
        const float4 w5 = ldg4(W0 + 5 * HH + c0);
        const float4 w6 = ldg4(W0 + 6 * HH + c0);
        const float4 w7 = ldg4(W0 + 7 * HH + c0);
#pragma unroll
        for (int pi = 0; pi < 4; ++pi) {
            const int p = 4 * wv + pi;
            const float s0 = __shfl(st0, p), s1 = __shfl(st1, p);
            const float f0 = __shfl(ft0, p), f1 = __shfl(ft1, p);
            const float f2 = __shfl(ft2, p), f3 = __shfl(ft3, p);
            const float f4 = __shfl(ft4, p), f5 = __shfl(ft5, p);
            float h[4];
#pragma unroll
            for (int j = 0; j < 4; ++j) {
                const float waj = ((const float*)&wa)[j], wbj = ((const float*)&wb)[j];
                float v = ((const float*)&bc)[j];
                v = fmaf(s0, waj, v);
                v = fmaf(s1, wbj, v);
                v = fmaf(f0, ((const float*)&w2)[j], v);
                v = fmaf(f1, ((const float*)&w3_)[j], v);
                v = fmaf(f2, ((const float*)&w4)[j], v);
                v = fmaf(f3, ((const float*)&w5)[j], v);
                v = fmaf(f4, ((const float*)&w6)[j], v);
                v = fmaf(f5, ((const float*)&w7)[j], v);
                h[j] = v;
            }
            short4v o;
#pragma unroll
            for (int j = 0; j < 4; ++j) o[j] = (short)f2bf(fmaxf(h[j], 0.0f));
            *(short4v*)&hA[p * SH + c0] = o;
        }
    }

    // preload cfeat for t=1 and seeds for t=0
    float4 cf = ldg4(cfeat + 256 + c0);
    float e0 = 0.0f, e1 = 0.0f;
    if (lane < 16) {
        const int gp = pbase + lane;
        e0 = path_seed[gp * 2 + 0];
        e1 = path_seed[gp * 2 + 1];
    }
    __syncthreads();                        // B0: hA + w3l ready

    for (int t = 0; t < LT; ++t) {
        layer4cg(wf1, bv1, hA, hB, wv, lane);   // h1 = relu(h0 @ W1 + b1)
        __syncthreads();                    // C
        layer4cg(wf2, bv2, hB, hC, wv, lane);   // h2 = relu(h1 @ W2 + b2)
        __syncthreads();                    // D

        // ---- layer 3: redundant in all 4 waves (B-frags from w3l) ----
        {
            float4v accA = {b3c, b3c, b3c, b3c};
            float4v accB = {0.0f, 0.0f, 0.0f, 0.0f};
            const unsigned short* arow = hC + col * SH + quad * 8;
#pragma unroll
            for (int ks = 0; ks < 4; ++ks) {
                short8 a0 = *(const short8*)(arow + ks * 32);
                short8 a1 = *(const short8*)(arow + (ks + 4) * 32);
                short8 b0f = *(const short8*)(w3l + (ks * 64 + lane) * 8);
                short8 b1f = *(const short8*)(w3l + ((ks + 4) * 64 + lane) * 8);
                accA = __builtin_amdgcn_mfma_f32_16x16x32_bf16(a0, b0f, accA, 0, 0, 0);
                accB = __builtin_amdgcn_mfma_f32_16x16x32_bf16(a1, b1f, accB, 0, 0, 0);
            }
            if (col < 5) {
#pragma unroll
                for (int r = 0; r < 4; ++r) sc[wv][quad * 4 + r][col] = accA[r] + accB[r];
            }
        }
        // intra-wave lgkmcnt ordering; sampling redundant in every wave
        if (lane < 16) {
            const int p = lane;
            const float mu0 = sc[wv][p][0];
            const float mu1 = sc[wv][p][1];
            const float s11 = softplus_fast(sc[wv][p][2]);
            const float s21 = sc[wv][p][3];
            const float s22 = softplus_fast(sc[wv][p][4]);
            const float n0 = softplus_fast(st0 + DTf * mu0 + SQ * (s11 * e0));
            const float n1 = softplus_fast(st1 + DTf * mu1 + SQ * (s21 * e0 + s22 * e1));
            st0 = n0;
            st1 = n1;
            if (wv == 0) {
                pbuf[p * 202 + (t + 1)] = n0;
                pbuf[p * 202 + 101 + (t + 1)] = n1;
                mbuf[p * 200 + t * 2 + 0] = mu0;
                mbuf[p * 200 + t * 2 + 1] = mu1;
                sbuf[p * 400 + t * 4 + 0] = s11;
                sbuf[p * 400 + t * 4 + 1] = 0.0f;
                sbuf[p * 400 + t * 4 + 2] = s21;
                sbuf[p * 400 + t * 4 + 3] = s22;
            }
        }

        // ---- layer 0 for t+1 (hA write: safe, all hA reads done at barrier C) ----
        if (t + 1 < LT) {
#pragma unroll
            for (int pi = 0; pi < 4; ++pi) {
                const int p = 4 * wv + pi;
                const float s0 = __shfl(st0, p), s1 = __shfl(st1, p);
                short4v o;
#pragma unroll
                for (int j = 0; j < 4; ++j) {
                    const float v = fmaf(s0, ((const float*)&wa)[j],
                                    fmaf(s1, ((const float*)&wb)[j], ((const float*)&cf)[j]));
                    o[j] = (short)f2bf(fmaxf(v, 0.0f));
                }
                *(short4v*)&hA[p * SH + c0] = o;
            }
            // prefetch next cfeat + next seeds (used next iteration)
            const int ti = (t + 2 < LT) ? (t + 2) : (LT - 1);
            cf = ldg4(cfeat + ti * 256 + c0);
            if (lane < 16) {
                const int gp = pbase + lane;
                e0 = path_seed[(size_t)(t + 1) * PP * 2 + gp * 2 + 0];
                e1 = path_seed[(size_t)(t + 1) * PP * 2 + gp * 2 + 1];
            }
        }
        __syncthreads();                    // B: h0(t+1) ready
    }

    // ---- coalesced output write phase ----
    float* __restrict__ pdst = out + (size_t)pbase * 202;
    float* __restrict__ mdst = out + (size_t)PP * 202 + (size_t)pbase * 200;
    float* __restrict__ sdst = out + (size_t)PP * 202 + (size_t)PP * 200 + (size_t)pbase * 400;
    for (int i = tid; i < PB * 202 / 4; i += NT) ((float4*)pdst)[i] = ((const float4*)pbuf)[i];
    for (int i = tid; i < PB * 200 / 4; i += NT) ((float4*)mdst)[i] = ((const float4*)mbuf)[i];
    for (int i = tid; i < PB * 400 / 4; i += NT) ((float4*)sdst)[i] = ((const float4*)sbuf)[i];
}

extern "C" void kernel_launch(void* const* d_in, const int* in_sizes, int n_in,
                              void* d_out, int out_size, void* d_ws, size_t ws_size,
                              hipStream_t stream) {
    (void)in_sizes; (void)n_in; (void)out_size; (void)ws_size;
    unsigned short* wt = (unsigned short*)d_ws;          // 135168 bf16 = 264 KB
    float* cfeat = (float*)(wt + 135168);                // 100*256 fp32 = 100 KB
    prep_weights<<<529, 256, 0, stream>>>(
        (const float*)d_in[0],   // W0
        (const float*)d_in[1],   // b0
        (const float*)d_in[2],   // W1
        (const float*)d_in[4],   // W2
        (const float*)d_in[6],   // W3
        (const float*)d_in[9],   // feature_init (t0)
        (const float*)d_in[10],  // tn_store
        (const float*)d_in[11],  // x1_store
        (const float*)d_in[12],  // x2_store
        wt, cfeat);
    lv_kernel<<<PP / PB, NT, 0, stream>>>(
        (const float*)d_in[0],   // W0
        (const float*)d_in[1],   // b0
        (const float*)d_in[3],   // b1
        (const float*)d_in[5],   // b2
        (const float*)d_in[7],   // b3
        (const float*)d_in[8],   // obs_init
        (const float*)d_in[9],   // feature_init
        (const float*)d_in[13],  // path_seed
        wt, cfeat,
        (float*)d_out);
}